// Round 5
// baseline (368.895 us; speedup 1.0000x reference)
//
#include <hip/hip_runtime.h>

#define F_N   150000
#define K_N   5
#define S_N   32
#define V_N   100000
#define NITER 5
#define MLP_N 330
#define SHIFTV (-500.0f)
#define W_ELL 48                         // max degree slack (Poisson mean 7.5)

#define FBLK  ((F_N + 255) / 256)        // 587
#define GBLK  ((V_N * 4 + 255) / 256)    // 1563  (4 threads per variable)

__device__ __forceinline__ float lse2(float a, float b) {
    float mx = fmaxf(a, b);
    return mx + __logf(__expf(a - mx) + __expf(b - mx));
}

// ---- fused: ELL slot-fill (only atomics in the pipeline) + m_1 init --------
__global__ __launch_bounds__(256) void k_fillinit(
    const float* __restrict__ prv_fb,   // [F][32]
    const float* __restrict__ prv_v2f,  // [F][5][2]
    const int*   __restrict__ vidx,     // [F][5]
    float2*      __restrict__ m_out,    // [5][F]
    int*         __restrict__ deg,      // [V] (zeroed before launch)
    int*         __restrict__ ell)      // [V][W_ELL]
{
    int f = blockIdx.x * 256 + threadIdx.x;
    if (f >= F_N) return;

    // ELL fill: 5 scattered device atomics per factor
    #pragma unroll
    for (int k = 0; k < K_N; ++k) {
        int v = vidx[f * K_N + k];
        int pos = atomicAdd(&deg[v], 1);
        if (pos < W_ELL) ell[v * W_ELL + pos] = k * F_N + f;
    }

    // m_1 math (hides under the atomic latency)
    float fb[S_N];
    const float4* p4 = reinterpret_cast<const float4*>(prv_fb + (size_t)f * S_N);
    #pragma unroll
    for (int i = 0; i < S_N / 4; ++i) {
        float4 v = p4[i];
        fb[i*4+0] = v.x; fb[i*4+1] = v.y; fb[i*4+2] = v.z; fb[i*4+3] = v.w;
    }
    float M = fb[0];
    #pragma unroll
    for (int s = 1; s < S_N; ++s) M = fmaxf(M, fb[s]);
    float T = 0.0f;
    float S0[K_N] = {0.f, 0.f, 0.f, 0.f, 0.f};
    #pragma unroll
    for (int s = 0; s < S_N; ++s) {
        float t = __expf(fb[s] - M);
        T += t;
        #pragma unroll
        for (int k = 0; k < K_N; ++k)
            if (((s >> k) & 1) == 0) S0[k] += t;
    }
    #pragma unroll
    for (int k = 0; k < K_N; ++k) {
        float v0 = prv_v2f[(size_t)f * (K_N*2) + k*2 + 0];
        float v1 = prv_v2f[(size_t)f * (K_N*2) + k*2 + 1];
        float u0 = __logf(S0[k])     - v0;
        float u1 = __logf(T - S0[k]) - v1;
        float l  = lse2(u0, u1);
        m_out[k*F_N + f] = make_float2(u0 - l, u1 - l);
    }
}

// ---- gather: vb = segsum(m) over ELL rows; var_term partial per block ------
__global__ __launch_bounds__(256) void k_gather(
    const float2* __restrict__ m,        // [5][F]
    const int*    __restrict__ deg,      // [V]
    const int*    __restrict__ ell,      // [V][W_ELL]
    float2*       __restrict__ vb,       // [V] raw
    float2*       __restrict__ cpart,    // [NITER][GBLK]
    int iter)
{
    __shared__ float2 wred[4];
    int t = blockIdx.x * 256 + threadIdx.x;
    int v = t >> 2, sub = t & 3;
    int lane = threadIdx.x & 63;

    float a0 = 0.0f, a1 = 0.0f;
    int n = 0;
    if (v < V_N) {
        n = deg[v];
        int nn = n < W_ELL ? n : W_ELL;
        const int* row = ell + (size_t)v * W_ELL;
        for (int i = sub; i < nn; i += 4) {
            float2 mm = m[row[i]];
            a0 += mm.x; a1 += mm.y;
        }
    }
    a0 += __shfl_xor(a0, 1); a1 += __shfl_xor(a1, 1);
    a0 += __shfl_xor(a0, 2); a1 += __shfl_xor(a1, 2);

    float c0 = 0.0f, c1 = 0.0f;
    if (v < V_N && sub == 0) {
        vb[v] = make_float2(a0, a1);
        float l = lse2(a0, a1);
        float b0 = a0 - l, b1 = a1 - l;
        float dm1 = (float)n - 1.0f;
        c0 = dm1 * __expf(b0) * b0;
        c1 = dm1 * __expf(b1) * b1;
    }
    #pragma unroll
    for (int mk = 32; mk >= 1; mk >>= 1) {
        c0 += __shfl_xor(c0, mk);
        c1 += __shfl_xor(c1, mk);
    }
    if (lane == 0) wred[threadIdx.x >> 6] = make_float2(c0, c1);
    __syncthreads();
    if (threadIdx.x == 0) {
        float2 s = wred[0];
        s.x += wred[1].x + wred[2].x + wred[3].x;
        s.y += wred[1].y + wred[2].y + wred[3].y;
        cpart[iter * GBLK + blockIdx.x] = s;
    }
}

// ---- fused factor iteration: zero atomics, register-lean -------------------
template <bool LAST>
__global__ __launch_bounds__(256) void k_iter(
    const float*  __restrict__ pot,      // [F][32]
    const int*    __restrict__ vidx,     // [F][5]
    float2*       __restrict__ m,        // [5][F], in-place update
    const float2* __restrict__ vb,       // [V] raw
    float*        __restrict__ fpart,    // [NITER][FBLK][64]
    int iter)
{
    const int lane = threadIdx.x & 63;
    __shared__ float red[256];

    int f = blockIdx.x * 256 + threadIdx.x;
    bool valid = f < F_N;
    int fc = valid ? f : (F_N - 1);

    float2 mm[K_N];
    #pragma unroll
    for (int k = 0; k < K_N; ++k) mm[k] = m[k*F_N + fc];
    int vi[K_N];
    #pragma unroll
    for (int k = 0; k < K_N; ++k) vi[k] = vidx[(size_t)fc * K_N + k];

    float v2f[K_N][2];
    #pragma unroll
    for (int k = 0; k < K_N; ++k) {
        float2 b = vb[vi[k]];
        float a0 = b.x - mm[k].x;
        float a1 = b.y - mm[k].y;
        float l = lse2(a0, a1);
        v2f[k][0] = a0 - l;
        v2f[k][1] = a1 - l;
    }

    // fb = pot + w   (pot recoverable later as fb - w: no potr array)
    float fb[S_N];
    const float4* p4 = reinterpret_cast<const float4*>(pot + (size_t)fc * S_N);
    #pragma unroll
    for (int i = 0; i < S_N / 4; ++i) {
        float4 pv = p4[i];
        int s = i * 4;
        fb[s+0] = pv.x + v2f[0][(s+0)&1] + v2f[1][((s+0)>>1)&1] + v2f[2][((s+0)>>2)&1] + v2f[3][((s+0)>>3)&1] + v2f[4][((s+0)>>4)&1];
        fb[s+1] = pv.y + v2f[0][(s+1)&1] + v2f[1][((s+1)>>1)&1] + v2f[2][((s+1)>>2)&1] + v2f[3][((s+1)>>3)&1] + v2f[4][((s+1)>>4)&1];
        fb[s+2] = pv.z + v2f[0][(s+2)&1] + v2f[1][((s+2)>>1)&1] + v2f[2][((s+2)>>2)&1] + v2f[3][((s+2)>>3)&1] + v2f[4][((s+2)>>4)&1];
        fb[s+3] = pv.w + v2f[0][(s+3)&1] + v2f[1][((s+3)>>1)&1] + v2f[2][((s+3)>>2)&1] + v2f[3][((s+3)>>3)&1] + v2f[4][((s+3)>>4)&1];
    }

    float M = fb[0];
    #pragma unroll
    for (int s = 1; s < S_N; ++s) M = fmaxf(M, fb[s]);

    float T = 0.0f;
    float S0[K_N] = {0.f, 0.f, 0.f, 0.f, 0.f};
    #pragma unroll
    for (int s = 0; s < S_N; ++s) {
        float t = __expf(fb[s] - M);
        T += t;
        #pragma unroll
        for (int k = 0; k < K_N; ++k)
            if (((s >> k) & 1) == 0) S0[k] += t;
    }

    if (!LAST) {
        #pragma unroll
        for (int k = 0; k < K_N; ++k) {
            float u0 = __logf(S0[k])     - v2f[k][0];
            float u1 = __logf(T - S0[k]) - v2f[k][1];
            float l  = lse2(u0, u1);
            if (valid) m[k*F_N + f] = make_float2(u0 - l, u1 - l);
        }
    }

    // features: energy[32] | fac_ent[32]
    float invT = 1.0f / T;
    float logT = __logf(T);
    float arr[2 * S_N];
    #pragma unroll
    for (int s = 0; s < S_N; ++s) {
        float p   = __expf(fb[s] - M) * invT;
        float fbn = fb[s] - M - logT;
        float w   = v2f[0][s&1] + v2f[1][(s>>1)&1] + v2f[2][(s>>2)&1]
                  + v2f[3][(s>>3)&1] + v2f[4][(s>>4)&1];
        float po  = fb[s] - w;                  // original potential
        arr[s]       = valid ? p * po   : 0.0f;
        arr[S_N + s] = valid ? -p * fbn : 0.0f;
    }

    // recursive halving: lane L ends holding total of feature L
    #pragma unroll
    for (int mk = 32; mk >= 1; mk >>= 1) {
        bool upper = (lane & mk) != 0;
        #pragma unroll
        for (int j = 0; j < mk; ++j) {
            float send = upper ? arr[j] : arr[j + mk];
            float recv = __shfl_xor(send, mk);
            float keep = upper ? arr[j + mk] : arr[j];
            arr[j] = keep + recv;
        }
    }

    red[threadIdx.x] = arr[0];
    __syncthreads();
    if (threadIdx.x < 64) {
        float s = red[threadIdx.x] + red[64 + threadIdx.x]
                + red[128 + threadIdx.x] + red[192 + threadIdx.x];
        fpart[((size_t)iter * FBLK + blockIdx.x) * 64 + threadIdx.x] = s;  // no atomics
    }
}

// ---- reduce fpart + cpart into x[330] --------------------------------------
__global__ __launch_bounds__(384) void k_vt(
    const float*  __restrict__ fpart,    // [NITER][FBLK][64]
    const float2* __restrict__ cpart,    // [NITER][GBLK]
    float*        __restrict__ x)        // [330]
{
    int t = threadIdx.x;
    if (t < 320) {
        int it = t >> 6, s = t & 63;       // wave w == iteration w: coalesced
        float acc = 0.0f;
        for (int b = 0; b < FBLK; ++b)
            acc += fpart[((size_t)it * FBLK + b) * 64 + s];
        x[it*66 + s] = acc;
    } else if (t < 330) {
        int idx = t - 320;
        int it = idx >> 1, c = idx & 1;
        float acc = 0.0f;
        for (int b = 0; b < GBLK; ++b) {
            float2 p = cpart[it * GBLK + b];
            acc += c ? p.y : p.x;
        }
        x[it*66 + 64 + c] = acc;
    }
}

// ---- MLP --------------------------------------------------------------------
__global__ __launch_bounds__(64) void k_mlp1(
    const float* __restrict__ x, const float* __restrict__ w1,
    const float* __restrict__ b1, float* __restrict__ h)
{
    int j = blockIdx.x;
    int lane = threadIdx.x;
    float s = 0.0f;
    for (int i = lane; i < MLP_N; i += 64) s += x[i] * w1[(size_t)j * MLP_N + i];
    #pragma unroll
    for (int mk = 32; mk >= 1; mk >>= 1) s += __shfl_xor(s, mk);
    if (lane == 0) h[j] = fmaxf(s + b1[j], SHIFTV);
}

__global__ __launch_bounds__(64) void k_mlp2(
    const float* __restrict__ h, const float* __restrict__ w2,
    const float* __restrict__ b2, float* __restrict__ out)
{
    int lane = threadIdx.x;
    float s = 0.0f;
    for (int i = lane; i < MLP_N; i += 64) s += h[i] * w2[i];
    #pragma unroll
    for (int mk = 32; mk >= 1; mk >>= 1) s += __shfl_xor(s, mk);
    if (lane == 0) out[0] = fmaxf(s + b2[0], SHIFTV);
}

// ---- launch ------------------------------------------------------------------
extern "C" void kernel_launch(void* const* d_in, const int* in_sizes, int n_in,
                              void* d_out, int out_size, void* d_ws, size_t ws_size,
                              hipStream_t stream)
{
    (void)in_sizes; (void)n_in; (void)out_size; (void)ws_size;
    const float* pot  = (const float*)d_in[0];
    const int*   vidx = (const int*)  d_in[1];
    const float* pv2f = (const float*)d_in[2];
    // d_in[3] = prv_f2v (unused by the reference)
    const float* pfb  = (const float*)d_in[4];
    const float* w1   = (const float*)d_in[5];
    const float* b1   = (const float*)d_in[6];
    const float* w2   = (const float*)d_in[7];
    const float* b2   = (const float*)d_in[8];

    // workspace layout
    float2* m     = (float2*)d_ws;                    // 5*F float2
    float2* vb    = m + 5 * F_N;                      // V float2
    float2* cpart = vb + V_N;                         // NITER*GBLK float2
    float*  fpart = (float*)(cpart + NITER * GBLK);   // NITER*FBLK*64
    float*  x     = fpart + (size_t)NITER * FBLK * 64;// 330
    float*  h     = x + MLP_N;                        // 330
    int*    ell   = (int*)(h + MLP_N);                // V*W_ELL
    int*    deg   = ell + (size_t)V_N * W_ELL;        // V (zeroed)

    hipMemsetAsync(deg, 0, V_N * sizeof(int), stream);

    k_fillinit<<<FBLK, 256, 0, stream>>>(pfb, pv2f, vidx, m, deg, ell);

    for (int it = 0; it < NITER; ++it) {
        k_gather<<<GBLK, 256, 0, stream>>>(m, deg, ell, vb, cpart, it);
        if (it < NITER - 1)
            k_iter<false><<<FBLK, 256, 0, stream>>>(pot, vidx, m, vb, fpart, it);
        else
            k_iter<true><<<FBLK, 256, 0, stream>>>(pot, vidx, m, vb, fpart, it);
    }

    k_vt<<<1, 384, 0, stream>>>(fpart, cpart, x);
    k_mlp1<<<MLP_N, 64, 0, stream>>>(x, w1, b1, h);
    k_mlp2<<<1, 64, 0, stream>>>(h, w2, b2, (float*)d_out);
}

// Round 6
// 236.435 us; speedup vs baseline: 1.5602x; 1.5602x over previous
//
#include <hip/hip_runtime.h>

#define F_N   150000
#define K_N   5
#define S_N   32
#define V_N   100000
#define NITER 5
#define MLP_N 330
#define SHIFTV (-500.0f)
#define W_ELL 32                         // max degree slack (Poisson mean 7.5; P(deg>32)~1e-11)

#define FBLK  ((F_N + 255) / 256)        // 587
#define GBLK  ((V_N * 4 + 255) / 256)    // 1563  (4 threads per variable)

__device__ __forceinline__ float lse2(float a, float b) {
    float mx = fmaxf(a, b);
    return mx + __logf(__expf(a - mx) + __expf(b - mx));
}

// ---- fused: ELL slot-fill (only atomics in the pipeline) + m_1 init --------
__global__ __launch_bounds__(256) void k_fillinit(
    const float* __restrict__ prv_fb,   // [F][32]
    const float* __restrict__ prv_v2f,  // [F][5][2]
    const int*   __restrict__ vidx,     // [F][5]
    float2*      __restrict__ m_out,    // [5][F]
    int*         __restrict__ deg,      // [V] (zeroed before launch)
    int*         __restrict__ ell)      // [V][W_ELL]
{
    int f = blockIdx.x * 256 + threadIdx.x;
    if (f >= F_N) return;

    // ELL fill: 5 scattered device atomics per factor
    #pragma unroll
    for (int k = 0; k < K_N; ++k) {
        int v = vidx[f * K_N + k];
        int pos = atomicAdd(&deg[v], 1);
        if (pos < W_ELL) ell[v * W_ELL + pos] = k * F_N + f;
    }

    // m_1 math (hides under the atomic latency)
    float fb[S_N];
    const float4* p4 = reinterpret_cast<const float4*>(prv_fb + (size_t)f * S_N);
    #pragma unroll
    for (int i = 0; i < S_N / 4; ++i) {
        float4 v = p4[i];
        fb[i*4+0] = v.x; fb[i*4+1] = v.y; fb[i*4+2] = v.z; fb[i*4+3] = v.w;
    }
    float M = fb[0];
    #pragma unroll
    for (int s = 1; s < S_N; ++s) M = fmaxf(M, fb[s]);
    float T = 0.0f;
    float S0[K_N] = {0.f, 0.f, 0.f, 0.f, 0.f};
    #pragma unroll
    for (int s = 0; s < S_N; ++s) {
        float t = __expf(fb[s] - M);
        T += t;
        #pragma unroll
        for (int k = 0; k < K_N; ++k)
            if (((s >> k) & 1) == 0) S0[k] += t;
    }
    #pragma unroll
    for (int k = 0; k < K_N; ++k) {
        float v0 = prv_v2f[(size_t)f * (K_N*2) + k*2 + 0];
        float v1 = prv_v2f[(size_t)f * (K_N*2) + k*2 + 1];
        float u0 = __logf(S0[k])     - v0;
        float u1 = __logf(T - S0[k]) - v1;
        float l  = lse2(u0, u1);
        m_out[k*F_N + f] = make_float2(u0 - l, u1 - l);
    }
}

// ---- gather: vb = segsum(m) over ELL rows; var_term partial per block ------
__global__ __launch_bounds__(256) void k_gather(
    const float2* __restrict__ m,        // [5][F]
    const int*    __restrict__ deg,      // [V]
    const int*    __restrict__ ell,      // [V][W_ELL]
    float2*       __restrict__ vb,       // [V] raw
    float2*       __restrict__ cpart,    // [NITER][GBLK]
    int iter)
{
    __shared__ float2 wred[4];
    int t = blockIdx.x * 256 + threadIdx.x;
    int v = t >> 2, sub = t & 3;
    int lane = threadIdx.x & 63;

    float a0 = 0.0f, a1 = 0.0f;
    int n = 0;
    if (v < V_N) {
        n = deg[v];
        int nn = n < W_ELL ? n : W_ELL;
        const int* row = ell + (size_t)v * W_ELL;
        for (int i = sub; i < nn; i += 4) {
            float2 mm = m[row[i]];
            a0 += mm.x; a1 += mm.y;
        }
    }
    a0 += __shfl_xor(a0, 1); a1 += __shfl_xor(a1, 1);
    a0 += __shfl_xor(a0, 2); a1 += __shfl_xor(a1, 2);

    float c0 = 0.0f, c1 = 0.0f;
    if (v < V_N && sub == 0) {
        vb[v] = make_float2(a0, a1);
        float l = lse2(a0, a1);
        float b0 = a0 - l, b1 = a1 - l;
        float dm1 = (float)n - 1.0f;
        c0 = dm1 * __expf(b0) * b0;
        c1 = dm1 * __expf(b1) * b1;
    }
    #pragma unroll
    for (int mk = 32; mk >= 1; mk >>= 1) {
        c0 += __shfl_xor(c0, mk);
        c1 += __shfl_xor(c1, mk);
    }
    if (lane == 0) wred[threadIdx.x >> 6] = make_float2(c0, c1);
    __syncthreads();
    if (threadIdx.x == 0) {
        float2 s = wred[0];
        s.x += wred[1].x + wred[2].x + wred[3].x;
        s.y += wred[1].y + wred[2].y + wred[3].y;
        cpart[iter * GBLK + blockIdx.x] = s;
    }
}

// ---- fused factor iteration: zero atomics ----------------------------------
template <bool LAST>
__global__ __launch_bounds__(256) void k_iter(
    const float*  __restrict__ pot,      // [F][32]
    const int*    __restrict__ vidx,     // [F][5]
    float2*       __restrict__ m,        // [5][F], in-place update
    const float2* __restrict__ vb,       // [V] raw
    float*        __restrict__ fpart,    // [NITER][FBLK][64]
    int iter)
{
    const int lane = threadIdx.x & 63;
    __shared__ float red[256];

    int f = blockIdx.x * 256 + threadIdx.x;
    bool valid = f < F_N;
    int fc = valid ? f : (F_N - 1);

    float2 mm[K_N];
    #pragma unroll
    for (int k = 0; k < K_N; ++k) mm[k] = m[k*F_N + fc];
    int vi[K_N];
    #pragma unroll
    for (int k = 0; k < K_N; ++k) vi[k] = vidx[(size_t)fc * K_N + k];

    float v2f[K_N][2];
    #pragma unroll
    for (int k = 0; k < K_N; ++k) {
        float2 b = vb[vi[k]];
        float a0 = b.x - mm[k].x;
        float a1 = b.y - mm[k].y;
        float l = lse2(a0, a1);
        v2f[k][0] = a0 - l;
        v2f[k][1] = a1 - l;
    }

    // fb = pot + w   (pot recoverable later as fb - w: no potr array)
    float fb[S_N];
    const float4* p4 = reinterpret_cast<const float4*>(pot + (size_t)fc * S_N);
    #pragma unroll
    for (int i = 0; i < S_N / 4; ++i) {
        float4 pv = p4[i];
        int s = i * 4;
        fb[s+0] = pv.x + v2f[0][(s+0)&1] + v2f[1][((s+0)>>1)&1] + v2f[2][((s+0)>>2)&1] + v2f[3][((s+0)>>3)&1] + v2f[4][((s+0)>>4)&1];
        fb[s+1] = pv.y + v2f[0][(s+1)&1] + v2f[1][((s+1)>>1)&1] + v2f[2][((s+1)>>2)&1] + v2f[3][((s+1)>>3)&1] + v2f[4][((s+1)>>4)&1];
        fb[s+2] = pv.z + v2f[0][(s+2)&1] + v2f[1][((s+2)>>1)&1] + v2f[2][((s+2)>>2)&1] + v2f[3][((s+2)>>3)&1] + v2f[4][((s+2)>>4)&1];
        fb[s+3] = pv.w + v2f[0][(s+3)&1] + v2f[1][((s+3)>>1)&1] + v2f[2][((s+3)>>2)&1] + v2f[3][((s+3)>>3)&1] + v2f[4][((s+3)>>4)&1];
    }

    float M = fb[0];
    #pragma unroll
    for (int s = 1; s < S_N; ++s) M = fmaxf(M, fb[s]);

    float T = 0.0f;
    float S0[K_N] = {0.f, 0.f, 0.f, 0.f, 0.f};
    #pragma unroll
    for (int s = 0; s < S_N; ++s) {
        float t = __expf(fb[s] - M);
        T += t;
        #pragma unroll
        for (int k = 0; k < K_N; ++k)
            if (((s >> k) & 1) == 0) S0[k] += t;
    }

    if (!LAST) {
        #pragma unroll
        for (int k = 0; k < K_N; ++k) {
            float u0 = __logf(S0[k])     - v2f[k][0];
            float u1 = __logf(T - S0[k]) - v2f[k][1];
            float l  = lse2(u0, u1);
            if (valid) m[k*F_N + f] = make_float2(u0 - l, u1 - l);
        }
    }

    // features: energy[32] | fac_ent[32]
    float invT = 1.0f / T;
    float logT = __logf(T);
    float arr[2 * S_N];
    #pragma unroll
    for (int s = 0; s < S_N; ++s) {
        float p   = __expf(fb[s] - M) * invT;
        float fbn = fb[s] - M - logT;
        float w   = v2f[0][s&1] + v2f[1][(s>>1)&1] + v2f[2][(s>>2)&1]
                  + v2f[3][(s>>3)&1] + v2f[4][(s>>4)&1];
        float po  = fb[s] - w;                  // original potential
        arr[s]       = valid ? p * po   : 0.0f;
        arr[S_N + s] = valid ? -p * fbn : 0.0f;
    }

    // recursive halving: lane L ends holding total of feature L
    #pragma unroll
    for (int mk = 32; mk >= 1; mk >>= 1) {
        bool upper = (lane & mk) != 0;
        #pragma unroll
        for (int j = 0; j < mk; ++j) {
            float send = upper ? arr[j] : arr[j + mk];
            float recv = __shfl_xor(send, mk);
            float keep = upper ? arr[j + mk] : arr[j];
            arr[j] = keep + recv;
        }
    }

    red[threadIdx.x] = arr[0];
    __syncthreads();
    if (threadIdx.x < 64) {
        float s = red[threadIdx.x] + red[64 + threadIdx.x]
                + red[128 + threadIdx.x] + red[192 + threadIdx.x];
        fpart[((size_t)iter * FBLK + blockIdx.x) * 64 + threadIdx.x] = s;  // no atomics
    }
}

// ---- parallel reduce fpart + cpart into x[330] -----------------------------
// blocks 0..319: feature (it = b>>6, s = b&63) over FBLK partials
// blocks 320..329: var_term (it, comp) over GBLK partials
__global__ __launch_bounds__(256) void k_vt(
    const float*  __restrict__ fpart,    // [NITER][FBLK][64]
    const float2* __restrict__ cpart,    // [NITER][GBLK]
    float*        __restrict__ x)        // [330]
{
    __shared__ float red[256];
    int b = blockIdx.x, t = threadIdx.x;
    float acc = 0.0f;
    if (b < 320) {
        int it = b >> 6, s = b & 63;
        for (int i = t; i < FBLK; i += 256)
            acc += fpart[((size_t)it * FBLK + i) * 64 + s];
    } else {
        int idx = b - 320;
        int it = idx >> 1, c = idx & 1;
        for (int i = t; i < GBLK; i += 256) {
            float2 p = cpart[it * GBLK + i];
            acc += c ? p.y : p.x;
        }
    }
    red[t] = acc;
    __syncthreads();
    #pragma unroll
    for (int off = 128; off >= 1; off >>= 1) {
        if (t < off) red[t] += red[t + off];
        __syncthreads();
    }
    if (t == 0) {
        if (b < 320) {
            int it = b >> 6, s = b & 63;
            x[it*66 + s] = red[0];
        } else {
            int idx = b - 320;
            int it = idx >> 1, c = idx & 1;
            x[it*66 + 64 + c] = red[0];
        }
    }
}

// ---- MLP --------------------------------------------------------------------
__global__ __launch_bounds__(64) void k_mlp1(
    const float* __restrict__ x, const float* __restrict__ w1,
    const float* __restrict__ b1, float* __restrict__ h)
{
    int j = blockIdx.x;
    int lane = threadIdx.x;
    float s = 0.0f;
    for (int i = lane; i < MLP_N; i += 64) s += x[i] * w1[(size_t)j * MLP_N + i];
    #pragma unroll
    for (int mk = 32; mk >= 1; mk >>= 1) s += __shfl_xor(s, mk);
    if (lane == 0) h[j] = fmaxf(s + b1[j], SHIFTV);
}

__global__ __launch_bounds__(64) void k_mlp2(
    const float* __restrict__ h, const float* __restrict__ w2,
    const float* __restrict__ b2, float* __restrict__ out)
{
    int lane = threadIdx.x;
    float s = 0.0f;
    for (int i = lane; i < MLP_N; i += 64) s += h[i] * w2[i];
    #pragma unroll
    for (int mk = 32; mk >= 1; mk >>= 1) s += __shfl_xor(s, mk);
    if (lane == 0) out[0] = fmaxf(s + b2[0], SHIFTV);
}

// ---- launch ------------------------------------------------------------------
extern "C" void kernel_launch(void* const* d_in, const int* in_sizes, int n_in,
                              void* d_out, int out_size, void* d_ws, size_t ws_size,
                              hipStream_t stream)
{
    (void)in_sizes; (void)n_in; (void)out_size; (void)ws_size;
    const float* pot  = (const float*)d_in[0];
    const int*   vidx = (const int*)  d_in[1];
    const float* pv2f = (const float*)d_in[2];
    // d_in[3] = prv_f2v (unused by the reference)
    const float* pfb  = (const float*)d_in[4];
    const float* w1   = (const float*)d_in[5];
    const float* b1   = (const float*)d_in[6];
    const float* w2   = (const float*)d_in[7];
    const float* b2   = (const float*)d_in[8];

    // workspace layout
    float2* m     = (float2*)d_ws;                    // 5*F float2
    float2* vb    = m + 5 * F_N;                      // V float2
    float2* cpart = vb + V_N;                         // NITER*GBLK float2
    float*  fpart = (float*)(cpart + NITER * GBLK);   // NITER*FBLK*64
    float*  x     = fpart + (size_t)NITER * FBLK * 64;// 330
    float*  h     = x + MLP_N;                        // 330
    int*    ell   = (int*)(h + MLP_N);                // V*W_ELL
    int*    deg   = ell + (size_t)V_N * W_ELL;        // V (zeroed)

    hipMemsetAsync(deg, 0, V_N * sizeof(int), stream);

    k_fillinit<<<FBLK, 256, 0, stream>>>(pfb, pv2f, vidx, m, deg, ell);

    for (int it = 0; it < NITER; ++it) {
        k_gather<<<GBLK, 256, 0, stream>>>(m, deg, ell, vb, cpart, it);
        if (it < NITER - 1)
            k_iter<false><<<FBLK, 256, 0, stream>>>(pot, vidx, m, vb, fpart, it);
        else
            k_iter<true><<<FBLK, 256, 0, stream>>>(pot, vidx, m, vb, fpart, it);
    }

    k_vt<<<330, 256, 0, stream>>>(fpart, cpart, x);
    k_mlp1<<<MLP_N, 64, 0, stream>>>(x, w1, b1, h);
    k_mlp2<<<1, 64, 0, stream>>>(h, w2, b2, (float*)d_out);
}

// Round 7
// 201.678 us; speedup vs baseline: 1.8291x; 1.1723x over previous
//
#include <hip/hip_runtime.h>

#define F_N   150000
#define K_N   5
#define S_N   32
#define V_N   100000
#define NITER 5
#define MLP_N 330
#define SHIFTV (-500.0f)
#define W_ELL 32                         // max degree slack (Poisson mean 7.5; P(deg>32)~1e-11)

#define FBLK  ((F_N + 255) / 256)        // 587
#define GBLK  ((V_N * 4 + 255) / 256)    // 1563  (4 threads per variable)
#define EBLK  ((F_N * K_N + 255) / 256)  // 2930 edge blocks
#define BBLK  (6 * FBLK)                 // 3522: 5/6 fill (2935>=2930) + 1/6 init (587)

__device__ __forceinline__ float lse2(float a, float b) {
    float mx = fmaxf(a, b);
    return mx + __logf(__expf(a - mx) + __expf(b - mx));
}

// ---- block-specialized: ELL fill (atomic pipe) || m_1 init (VALU/VMEM) -----
__global__ __launch_bounds__(256) void k_build(
    const float* __restrict__ prv_fb,   // [F][32]
    const float* __restrict__ prv_v2f,  // [F][5][2]
    const int*   __restrict__ vidx,     // [F][5]
    float2*      __restrict__ m_out,    // [5][F]
    int*         __restrict__ deg,      // [V] (zeroed before launch)
    int*         __restrict__ ell)      // [V][W_ELL]
{
    int g = blockIdx.x / 6, r = blockIdx.x % 6;

    if (r < 5) {
        // ---- ELL fill: one edge per thread, one independent atomic ----
        int e = (g * 5 + r) * 256 + threadIdx.x;
        if (e >= F_N * K_N) return;
        int v = vidx[e];
        int f = e / K_N;
        int k = e - f * K_N;
        int pos = atomicAdd(&deg[v], 1);
        if (pos < W_ELL) ell[v * W_ELL + pos] = k * F_N + f;
        return;
    }

    // ---- m_1 init: pure math + coalesced memory ----
    int f = g * 256 + threadIdx.x;
    if (f >= F_N) return;

    float fb[S_N];
    const float4* p4 = reinterpret_cast<const float4*>(prv_fb + (size_t)f * S_N);
    #pragma unroll
    for (int i = 0; i < S_N / 4; ++i) {
        float4 v = p4[i];
        fb[i*4+0] = v.x; fb[i*4+1] = v.y; fb[i*4+2] = v.z; fb[i*4+3] = v.w;
    }
    float M = fb[0];
    #pragma unroll
    for (int s = 1; s < S_N; ++s) M = fmaxf(M, fb[s]);
    float T = 0.0f;
    float S0[K_N] = {0.f, 0.f, 0.f, 0.f, 0.f};
    #pragma unroll
    for (int s = 0; s < S_N; ++s) {
        float t = __expf(fb[s] - M);
        T += t;
        #pragma unroll
        for (int k = 0; k < K_N; ++k)
            if (((s >> k) & 1) == 0) S0[k] += t;
    }
    #pragma unroll
    for (int k = 0; k < K_N; ++k) {
        float v0 = prv_v2f[(size_t)f * (K_N*2) + k*2 + 0];
        float v1 = prv_v2f[(size_t)f * (K_N*2) + k*2 + 1];
        float u0 = __logf(S0[k])     - v0;
        float u1 = __logf(T - S0[k]) - v1;
        float l  = lse2(u0, u1);
        m_out[k*F_N + f] = make_float2(u0 - l, u1 - l);
    }
}

// ---- gather: vb = segsum(m) over ELL rows; var_term partial per block ------
__global__ __launch_bounds__(256) void k_gather(
    const float2* __restrict__ m,        // [5][F]
    const int*    __restrict__ deg,      // [V]
    const int*    __restrict__ ell,      // [V][W_ELL]
    float2*       __restrict__ vb,       // [V] raw
    float2*       __restrict__ cpart,    // [NITER][GBLK]
    int iter)
{
    __shared__ float2 wred[4];
    int t = blockIdx.x * 256 + threadIdx.x;
    int v = t >> 2, sub = t & 3;
    int lane = threadIdx.x & 63;

    float a0 = 0.0f, a1 = 0.0f;
    int n = 0;
    if (v < V_N) {
        n = deg[v];
        int nn = n < W_ELL ? n : W_ELL;
        const int* row = ell + (size_t)v * W_ELL;
        for (int i = sub; i < nn; i += 4) {
            float2 mm = m[row[i]];
            a0 += mm.x; a1 += mm.y;
        }
    }
    a0 += __shfl_xor(a0, 1); a1 += __shfl_xor(a1, 1);
    a0 += __shfl_xor(a0, 2); a1 += __shfl_xor(a1, 2);

    float c0 = 0.0f, c1 = 0.0f;
    if (v < V_N && sub == 0) {
        vb[v] = make_float2(a0, a1);
        float l = lse2(a0, a1);
        float b0 = a0 - l, b1 = a1 - l;
        float dm1 = (float)n - 1.0f;
        c0 = dm1 * __expf(b0) * b0;
        c1 = dm1 * __expf(b1) * b1;
    }
    #pragma unroll
    for (int mk = 32; mk >= 1; mk >>= 1) {
        c0 += __shfl_xor(c0, mk);
        c1 += __shfl_xor(c1, mk);
    }
    if (lane == 0) wred[threadIdx.x >> 6] = make_float2(c0, c1);
    __syncthreads();
    if (threadIdx.x == 0) {
        float2 s = wred[0];
        s.x += wred[1].x + wred[2].x + wred[3].x;
        s.y += wred[1].y + wred[2].y + wred[3].y;
        cpart[iter * GBLK + blockIdx.x] = s;
    }
}

// ---- fused factor iteration: zero atomics ----------------------------------
template <bool LAST>
__global__ __launch_bounds__(256) void k_iter(
    const float*  __restrict__ pot,      // [F][32]
    const int*    __restrict__ vidx,     // [F][5]
    float2*       __restrict__ m,        // [5][F], in-place update
    const float2* __restrict__ vb,       // [V] raw
    float*        __restrict__ fpart,    // [NITER][FBLK][64]
    int iter)
{
    const int lane = threadIdx.x & 63;
    __shared__ float red[256];

    int f = blockIdx.x * 256 + threadIdx.x;
    bool valid = f < F_N;
    int fc = valid ? f : (F_N - 1);

    float2 mm[K_N];
    #pragma unroll
    for (int k = 0; k < K_N; ++k) mm[k] = m[k*F_N + fc];
    int vi[K_N];
    #pragma unroll
    for (int k = 0; k < K_N; ++k) vi[k] = vidx[(size_t)fc * K_N + k];

    float v2f[K_N][2];
    #pragma unroll
    for (int k = 0; k < K_N; ++k) {
        float2 b = vb[vi[k]];
        float a0 = b.x - mm[k].x;
        float a1 = b.y - mm[k].y;
        float l = lse2(a0, a1);
        v2f[k][0] = a0 - l;
        v2f[k][1] = a1 - l;
    }

    // fb = pot + w   (pot recoverable later as fb - w: no potr array)
    float fb[S_N];
    const float4* p4 = reinterpret_cast<const float4*>(pot + (size_t)fc * S_N);
    #pragma unroll
    for (int i = 0; i < S_N / 4; ++i) {
        float4 pv = p4[i];
        int s = i * 4;
        fb[s+0] = pv.x + v2f[0][(s+0)&1] + v2f[1][((s+0)>>1)&1] + v2f[2][((s+0)>>2)&1] + v2f[3][((s+0)>>3)&1] + v2f[4][((s+0)>>4)&1];
        fb[s+1] = pv.y + v2f[0][(s+1)&1] + v2f[1][((s+1)>>1)&1] + v2f[2][((s+1)>>2)&1] + v2f[3][((s+1)>>3)&1] + v2f[4][((s+1)>>4)&1];
        fb[s+2] = pv.z + v2f[0][(s+2)&1] + v2f[1][((s+2)>>1)&1] + v2f[2][((s+2)>>2)&1] + v2f[3][((s+2)>>3)&1] + v2f[4][((s+2)>>4)&1];
        fb[s+3] = pv.w + v2f[0][(s+3)&1] + v2f[1][((s+3)>>1)&1] + v2f[2][((s+3)>>2)&1] + v2f[3][((s+3)>>3)&1] + v2f[4][((s+3)>>4)&1];
    }

    float M = fb[0];
    #pragma unroll
    for (int s = 1; s < S_N; ++s) M = fmaxf(M, fb[s]);

    float T = 0.0f;
    float S0[K_N] = {0.f, 0.f, 0.f, 0.f, 0.f};
    #pragma unroll
    for (int s = 0; s < S_N; ++s) {
        float t = __expf(fb[s] - M);
        T += t;
        #pragma unroll
        for (int k = 0; k < K_N; ++k)
            if (((s >> k) & 1) == 0) S0[k] += t;
    }

    if (!LAST) {
        #pragma unroll
        for (int k = 0; k < K_N; ++k) {
            float u0 = __logf(S0[k])     - v2f[k][0];
            float u1 = __logf(T - S0[k]) - v2f[k][1];
            float l  = lse2(u0, u1);
            if (valid) m[k*F_N + f] = make_float2(u0 - l, u1 - l);
        }
    }

    // features: energy[32] | fac_ent[32]
    float invT = 1.0f / T;
    float logT = __logf(T);
    float arr[2 * S_N];
    #pragma unroll
    for (int s = 0; s < S_N; ++s) {
        float p   = __expf(fb[s] - M) * invT;
        float fbn = fb[s] - M - logT;
        float w   = v2f[0][s&1] + v2f[1][(s>>1)&1] + v2f[2][(s>>2)&1]
                  + v2f[3][(s>>3)&1] + v2f[4][(s>>4)&1];
        float po  = fb[s] - w;                  // original potential
        arr[s]       = valid ? p * po   : 0.0f;
        arr[S_N + s] = valid ? -p * fbn : 0.0f;
    }

    // recursive halving: lane L ends holding total of feature L
    #pragma unroll
    for (int mk = 32; mk >= 1; mk >>= 1) {
        bool upper = (lane & mk) != 0;
        #pragma unroll
        for (int j = 0; j < mk; ++j) {
            float send = upper ? arr[j] : arr[j + mk];
            float recv = __shfl_xor(send, mk);
            float keep = upper ? arr[j + mk] : arr[j];
            arr[j] = keep + recv;
        }
    }

    red[threadIdx.x] = arr[0];
    __syncthreads();
    if (threadIdx.x < 64) {
        float s = red[threadIdx.x] + red[64 + threadIdx.x]
                + red[128 + threadIdx.x] + red[192 + threadIdx.x];
        fpart[((size_t)iter * FBLK + blockIdx.x) * 64 + threadIdx.x] = s;  // no atomics
    }
}

// ---- parallel reduce fpart + cpart into x[330] -----------------------------
__global__ __launch_bounds__(256) void k_vt(
    const float*  __restrict__ fpart,    // [NITER][FBLK][64]
    const float2* __restrict__ cpart,    // [NITER][GBLK]
    float*        __restrict__ x)        // [330]
{
    __shared__ float red[256];
    int b = blockIdx.x, t = threadIdx.x;
    float acc = 0.0f;
    if (b < 320) {
        int it = b >> 6, s = b & 63;
        for (int i = t; i < FBLK; i += 256)
            acc += fpart[((size_t)it * FBLK + i) * 64 + s];
    } else {
        int idx = b - 320;
        int it = idx >> 1, c = idx & 1;
        for (int i = t; i < GBLK; i += 256) {
            float2 p = cpart[it * GBLK + i];
            acc += c ? p.y : p.x;
        }
    }
    red[t] = acc;
    __syncthreads();
    #pragma unroll
    for (int off = 128; off >= 1; off >>= 1) {
        if (t < off) red[t] += red[t + off];
        __syncthreads();
    }
    if (t == 0) {
        if (b < 320) {
            int it = b >> 6, s = b & 63;
            x[it*66 + s] = red[0];
        } else {
            int idx = b - 320;
            int it = idx >> 1, c = idx & 1;
            x[it*66 + 64 + c] = red[0];
        }
    }
}

// ---- MLP --------------------------------------------------------------------
__global__ __launch_bounds__(64) void k_mlp1(
    const float* __restrict__ x, const float* __restrict__ w1,
    const float* __restrict__ b1, float* __restrict__ h)
{
    int j = blockIdx.x;
    int lane = threadIdx.x;
    float s = 0.0f;
    for (int i = lane; i < MLP_N; i += 64) s += x[i] * w1[(size_t)j * MLP_N + i];
    #pragma unroll
    for (int mk = 32; mk >= 1; mk >>= 1) s += __shfl_xor(s, mk);
    if (lane == 0) h[j] = fmaxf(s + b1[j], SHIFTV);
}

__global__ __launch_bounds__(64) void k_mlp2(
    const float* __restrict__ h, const float* __restrict__ w2,
    const float* __restrict__ b2, float* __restrict__ out)
{
    int lane = threadIdx.x;
    float s = 0.0f;
    for (int i = lane; i < MLP_N; i += 64) s += h[i] * w2[i];
    #pragma unroll
    for (int mk = 32; mk >= 1; mk >>= 1) s += __shfl_xor(s, mk);
    if (lane == 0) out[0] = fmaxf(s + b2[0], SHIFTV);
}

// ---- launch ------------------------------------------------------------------
extern "C" void kernel_launch(void* const* d_in, const int* in_sizes, int n_in,
                              void* d_out, int out_size, void* d_ws, size_t ws_size,
                              hipStream_t stream)
{
    (void)in_sizes; (void)n_in; (void)out_size; (void)ws_size;
    const float* pot  = (const float*)d_in[0];
    const int*   vidx = (const int*)  d_in[1];
    const float* pv2f = (const float*)d_in[2];
    // d_in[3] = prv_f2v (unused by the reference)
    const float* pfb  = (const float*)d_in[4];
    const float* w1   = (const float*)d_in[5];
    const float* b1   = (const float*)d_in[6];
    const float* w2   = (const float*)d_in[7];
    const float* b2   = (const float*)d_in[8];

    // workspace layout
    float2* m     = (float2*)d_ws;                    // 5*F float2
    float2* vb    = m + 5 * F_N;                      // V float2
    float2* cpart = vb + V_N;                         // NITER*GBLK float2
    float*  fpart = (float*)(cpart + NITER * GBLK);   // NITER*FBLK*64
    float*  x     = fpart + (size_t)NITER * FBLK * 64;// 330
    float*  h     = x + MLP_N;                        // 330
    int*    ell   = (int*)(h + MLP_N);                // V*W_ELL
    int*    deg   = ell + (size_t)V_N * W_ELL;        // V (zeroed)

    hipMemsetAsync(deg, 0, V_N * sizeof(int), stream);

    k_build<<<BBLK, 256, 0, stream>>>(pfb, pv2f, vidx, m, deg, ell);

    for (int it = 0; it < NITER; ++it) {
        k_gather<<<GBLK, 256, 0, stream>>>(m, deg, ell, vb, cpart, it);
        if (it < NITER - 1)
            k_iter<false><<<FBLK, 256, 0, stream>>>(pot, vidx, m, vb, fpart, it);
        else
            k_iter<true><<<FBLK, 256, 0, stream>>>(pot, vidx, m, vb, fpart, it);
    }

    k_vt<<<330, 256, 0, stream>>>(fpart, cpart, x);
    k_mlp1<<<MLP_N, 64, 0, stream>>>(x, w1, b1, h);
    k_mlp2<<<1, 64, 0, stream>>>(h, w2, b2, (float*)d_out);
}